// Round 8
// baseline (429.911 us; speedup 1.0000x reference)
//
#include <hip/hip_runtime.h>
#include <cstdint>
#include <cstddef>

// ---------------------------------------------------------------------------
// PointNetFeaturePropagation: 3-NN interpolation + Linear + BatchNorm1d
// B=4 N=16384 S=4096 D=64
//
// R0-R6: never benched (8 consecutive GPU-infra failures); design is
// paper-audited only. R7 = audit + FREEZE of the R6 design: no structural
// changes without a measurement (churn risk > unmeasured gain).
//
// Design summary:
//  K0 prep:        pts4 = (x,y,z,|p|^2) per xyz2 point; zero BN accum.
//  K1 knn_interp:  lane-pair scan (lanes 2i/2i+1 = chunk 0/1 of one query,
//                  2048 cands each) -> 2048 waves (2/SIMD latency cover);
//                  vector candidate loads (2 distinct 16B lines/wave-instr);
//                  wave-uniform __any early-out around self-predicating
//                  branchless top-3 insert (taken ~0.32/chunk);
//                  key d = fma(-2,dot, add(q2,p2)), dot = asc-k fma chain
//                  (EXACT reference rounding); pair merge via 6 shfl_xor +
//                  3 strict-'<' inserts (top_k tie-break preserved);
//                  fused weights + points2 gather + interp row write.
//  K3 linear:      lane = out-channel, W row in VGPRs, wave-uniform row
//                  broadcast loads; per-channel BN sum/sumsq via atomics.
//  K4 bn_final:    training-mode BN finalize, float4 HBM streaming.
//
// Open numerics risk (flagged, not fixable without a bench): XLA's dot
// lowering variant. If first bench fails absmax with FEW LARGE outlier rows
// -> switch dot to separate mul+adds and re-bench.
// Perf prediction: K1 34-37us (VALUBusy 78-88%, MfmaUtil 0), K3 ~4us,
// K4 ~5us, K0 ~1us; total 45-50us.
// ---------------------------------------------------------------------------

#define BB 4
#define NN 16384
#define SS 4096
#define DD 64
#define TQ (BB * NN)          // 65536 queries
#define CHUNK (SS / 2)        // 2048 candidates per lane of a pair
#define FLT_BIG 3.4028235e38f

// Branchless top-3 insert; strict '<' keeps first-seen on ties (matches
// jax.lax.top_k tie-break = lowest index, given insertion in index order).
static __device__ __forceinline__ void ins3(float dd, int ii,
                                            float& d0, float& d1, float& d2,
                                            int& i0, int& i1, int& i2) {
  bool l0 = dd < d0, l1 = dd < d1, l2 = dd < d2;
  d2 = l1 ? d1 : (l2 ? dd : d2);  i2 = l1 ? i1 : (l2 ? ii : i2);
  d1 = l0 ? d0 : (l1 ? dd : d1);  i1 = l0 ? i0 : (l1 ? ii : i1);
  d0 = l0 ? dd : d0;              i0 = l0 ? ii : i0;
}

// K0: build (x, y, z, |p|^2) float4 per xyz2 point; zero BN accumulators.
// |p|^2 rounding mimics XLA: three muls, then ((x2+y2)+z2).
__global__ __launch_bounds__(256) void prep(const float* __restrict__ xyz2,
                                            float4* __restrict__ pts4,
                                            float* __restrict__ accum) {
  const int i = (int)blockIdx.x * 256 + (int)threadIdx.x;  // 16384 points total
  if (blockIdx.x == 0 && threadIdx.x < 128) accum[threadIdx.x] = 0.0f;
  float x = xyz2[3 * i], y = xyz2[3 * i + 1], z = xyz2[3 * i + 2];
  float p2 = __fadd_rn(__fadd_rn(__fmul_rn(x, x), __fmul_rn(y, y)), __fmul_rn(z, z));
  pts4[i] = make_float4(x, y, z, p2);
}

// K1 (fused): 3-NN + inverse-distance interpolation, lane-pair layout.
__global__ __launch_bounds__(256) void knn_interp(const float* __restrict__ xyz1,
                                                  const float4* __restrict__ pts4,
                                                  const float* __restrict__ points2,
                                                  float* __restrict__ interp) {
  const int lane  = (int)threadIdx.x & 63;
  const int gw    = (int)blockIdx.x * 4 + ((int)threadIdx.x >> 6);  // 0..2047
  const int q     = gw * 32 + (lane >> 1);
  const int chunk = lane & 1;
  // 32-aligned query ranges never cross a batch boundary; SGPR residency
  const int batch = __builtin_amdgcn_readfirstlane(q >> 14);

  const float qx = xyz1[3 * q], qy = xyz1[3 * q + 1], qz = xyz1[3 * q + 2];
  const float q2 = __fadd_rn(__fadd_rn(__fmul_rn(qx, qx), __fmul_rn(qy, qy)), __fmul_rn(qz, qz));
  const float4* __restrict__ cp = pts4 + (size_t)batch * SS + (size_t)chunk * CHUNK;

  float d0 = FLT_BIG, d1 = FLT_BIG, d2v = FLT_BIG;
  int j0 = 0, j1 = 0, j2 = 0;

#pragma unroll 16
  for (int s = 0; s < CHUNK; ++s) {
    float4 p = cp[s];  // 2 distinct 16B lines per wave-load; VGPR prefetch
    float dot = __fmaf_rn(qz, p.z, __fmaf_rn(qy, p.y, __fmul_rn(qx, p.x)));
    float dd  = __fmaf_rn(-2.0f, dot, __fadd_rn(q2, p.w));
    if (__any(dd < d2v)) {        // wave-uniform gate -> s_cbranch, no if-convert
      ins3(dd, s, d0, d1, d2v, j0, j1, j2);  // self-predicating per lane
    }
  }

  // globalize indices within the batch
  const int sb = chunk * CHUNK;
  j0 += sb; j1 += sb; j2 += sb;

  // pair merge: pull partner's sorted triple; even lane (chunk 0, lower
  // indices) inserts partner items (all higher-index) with strict '<' ->
  // correct top_k tie-break. Odd lanes compute a wrong-tie-break merge that
  // is discarded by the broadcast below.
  float e0 = __shfl_xor(d0, 1, 64), e1 = __shfl_xor(d1, 1, 64), e2 = __shfl_xor(d2v, 1, 64);
  int   k0 = __shfl_xor(j0, 1, 64), k1 = __shfl_xor(j1, 1, 64), k2 = __shfl_xor(j2, 1, 64);
  ins3(e0, k0, d0, d1, d2v, j0, j1, j2);
  ins3(e1, k1, d0, d1, d2v, j0, j1, j2);
  ins3(e2, k2, d0, d1, d2v, j0, j1, j2);

  // broadcast the even lane's merged result to its pair partner
  const int src = lane & 62;
  d0  = __shfl(d0, src, 64);  d1 = __shfl(d1, src, 64);  d2v = __shfl(d2v, src, 64);
  j0  = __shfl(j0, src, 64);  j1 = __shfl(j1, src, 64);  j2  = __shfl(j2, src, 64);

  // weights: 1/(d+1e-8) (IEEE div), normalized by true div — reference order
  float r0 = 1.0f / __fadd_rn(d0, 1e-8f);
  float r1 = 1.0f / __fadd_rn(d1, 1e-8f);
  float r2 = 1.0f / __fadd_rn(d2v, 1e-8f);
  float rs = __fadd_rn(__fadd_rn(r0, r1), r2);
  float w0 = r0 / rs, w1 = r1 / rs, w2 = r2 / rs;

  // gather + blend: pair splits the 16 float4s of the row (8 each)
  const float* p2b = points2 + (size_t)batch * SS * DD;
  const float4* g0 = (const float4*)(p2b + (size_t)j0 * DD);
  const float4* g1 = (const float4*)(p2b + (size_t)j1 * DD);
  const float4* g2 = (const float4*)(p2b + (size_t)j2 * DD);
  float4* op = (float4*)(interp + (size_t)q * DD);
  const int kbase = chunk * 8;
#pragma unroll
  for (int k = 0; k < 8; ++k) {
    const int kk = kbase + k;
    float4 a = g0[kk], b = g1[kk], c = g2[kk], r;
    // sum over the 3-neighbor axis: ((g0*w0 + g1*w1) + g2*w2), XLA reduce order
    r.x = __fadd_rn(__fadd_rn(__fmul_rn(a.x, w0), __fmul_rn(b.x, w1)), __fmul_rn(c.x, w2));
    r.y = __fadd_rn(__fadd_rn(__fmul_rn(a.y, w0), __fmul_rn(b.y, w1)), __fmul_rn(c.y, w2));
    r.z = __fadd_rn(__fadd_rn(__fmul_rn(a.z, w0), __fmul_rn(b.z, w1)), __fmul_rn(c.z, w2));
    r.w = __fadd_rn(__fadd_rn(__fmul_rn(a.w, w0), __fmul_rn(b.w, w1)), __fmul_rn(c.w, w2));
    op[kk] = r;
  }
}

// K3: Linear out[q][e] = sum_d interp[q][d] * W[e][d] + b[e].  lane = e;
// W row (64 floats) in VGPRs; interp row addresses are wave-uniform
// (broadcast loads). Per-channel sum/sumsq accumulated for BN via device
// atomics (ordering nondeterminism ~1e-8 on mean; BN is continuous — safe).
// Stamped out twice: RQ (restrict, primary: interp in ws) and MA (may-alias
// fallback: interp==out; row q fully read before its store).
#define K3_BODY(QUAL)                                                          \
  const int lane = (int)threadIdx.x & 63;                                      \
  int gw = (int)blockIdx.x * 4 + ((int)threadIdx.x >> 6); /* 0..2047 */        \
  gw = __builtin_amdgcn_readfirstlane(gw);                                     \
  float wreg[DD];                                                              \
  const float4* wr = (const float4*)(W + (size_t)lane * DD);                   \
  _Pragma("unroll")                                                            \
  for (int k = 0; k < DD / 4; ++k) {                                           \
    float4 t = wr[k];                                                          \
    wreg[4 * k] = t.x; wreg[4 * k + 1] = t.y;                                  \
    wreg[4 * k + 2] = t.z; wreg[4 * k + 3] = t.w;                              \
  }                                                                            \
  const float bv = bias[lane];                                                 \
  float bsum = 0.0f, bsq = 0.0f;                                               \
  for (int j = 0; j < 32; ++j) { /* 32 rows per wave */                        \
    const int q = (gw << 5) + j;                                               \
    const float4* QUAL ip4 = (const float4*)(interp + (size_t)q * DD);         \
    float acc = 0.0f;                                                          \
    _Pragma("unroll")                                                          \
    for (int k = 0; k < DD / 4; ++k) {                                         \
      float4 t = ip4[k];                                                       \
      acc = __fmaf_rn(t.x, wreg[4 * k], acc);                                  \
      acc = __fmaf_rn(t.y, wreg[4 * k + 1], acc);                              \
      acc = __fmaf_rn(t.z, wreg[4 * k + 2], acc);                              \
      acc = __fmaf_rn(t.w, wreg[4 * k + 3], acc);                              \
    }                                                                          \
    float ov = __fadd_rn(acc, bv);                                             \
    out[(size_t)q * DD + lane] = ov;                                           \
    bsum = __fadd_rn(bsum, ov);                                                \
    bsq  = __fmaf_rn(ov, ov, bsq);                                             \
  }                                                                            \
  atomicAdd(&accum[lane], bsum);                                               \
  atomicAdd(&accum[DD + lane], bsq);

__global__ __launch_bounds__(256) void linear_bnstats_rq(
    const float* __restrict__ interp, const float* __restrict__ W,
    const float* __restrict__ bias, float* __restrict__ out,
    float* __restrict__ accum) {
  K3_BODY(__restrict__)
}

__global__ __launch_bounds__(256) void linear_bnstats_ma(
    const float* interp, const float* __restrict__ W,
    const float* __restrict__ bias, float* out,
    float* __restrict__ accum) {
  K3_BODY()
}

// K4: BatchNorm finalize; float4 per thread (HBM streaming, 32 MB).
// out = ((gamma*(v-m))*rstd) + beta  — reference association preserved.
__global__ __launch_bounds__(256) void bn_final(float* __restrict__ out,
                                                const float* __restrict__ accum,
                                                const float* __restrict__ gamma,
                                                const float* __restrict__ beta) {
  const int i4 = (int)blockIdx.x * 256 + (int)threadIdx.x;  // 1048576 float4s
  const int e0 = (i4 * 4) & 63;                             // 4 consecutive channels
  const float inv = 1.0f / (float)TQ;

  float4 v  = ((const float4*)out)[i4];
  float4 sm = *(const float4*)(accum + e0);
  float4 sq = *(const float4*)(accum + DD + e0);
  float4 g  = *(const float4*)(gamma + e0);
  float4 bt = *(const float4*)(beta + e0);

  float4 r;
  {
    float m = sm.x * inv, va = __fmaf_rn(-m, m, sq.x * inv);
    r.x = __fadd_rn(__fmul_rn(__fmul_rn(g.x, __fsub_rn(v.x, m)), rsqrtf(va + 1e-5f)), bt.x);
  }
  {
    float m = sm.y * inv, va = __fmaf_rn(-m, m, sq.y * inv);
    r.y = __fadd_rn(__fmul_rn(__fmul_rn(g.y, __fsub_rn(v.y, m)), rsqrtf(va + 1e-5f)), bt.y);
  }
  {
    float m = sm.z * inv, va = __fmaf_rn(-m, m, sq.z * inv);
    r.z = __fadd_rn(__fmul_rn(__fmul_rn(g.z, __fsub_rn(v.z, m)), rsqrtf(va + 1e-5f)), bt.z);
  }
  {
    float m = sm.w * inv, va = __fmaf_rn(-m, m, sq.w * inv);
    r.w = __fadd_rn(__fmul_rn(__fmul_rn(g.w, __fsub_rn(v.w, m)), rsqrtf(va + 1e-5f)), bt.w);
  }
  ((float4*)out)[i4] = r;
}

extern "C" void kernel_launch(void* const* d_in, const int* in_sizes, int n_in,
                              void* d_out, int out_size, void* d_ws, size_t ws_size,
                              hipStream_t stream) {
  const float* xyz1    = (const float*)d_in[0];
  const float* xyz2    = (const float*)d_in[1];
  // d_in[2] = points1 (unused in this module variant)
  const float* points2 = (const float*)d_in[3];
  const float* W       = (const float*)d_in[4];
  const float* bias    = (const float*)d_in[5];
  const float* gamma   = (const float*)d_in[6];
  const float* beta    = (const float*)d_in[7];
  float* out = (float*)d_out;

  // workspace carve-up (byte offsets, 16B-aligned):
  //   pts4   @ 0      : B*S float4   = 262144 B
  //   accum  @ 262144 : 128 floats   =    512 B
  //   interp @ 262656 : TQ*DD floats = 16 MiB   (if ws_size permits)
  char* ws = (char*)d_ws;
  float4* pts4 = (float4*)ws;
  float* accum = (float*)(ws + 262144);
  const size_t need = 262656 + (size_t)TQ * DD * sizeof(float);
  const bool ws_interp = (ws_size >= need);
  float* interp = ws_interp ? (float*)(ws + 262656) : out;

  prep<<<dim3((BB * SS) / 256), dim3(256), 0, stream>>>(xyz2, pts4, accum);
  // 2 threads per query: TQ*2/256 = 512 blocks
  knn_interp<<<dim3((TQ * 2) / 256), dim3(256), 0, stream>>>(xyz1, pts4, points2, interp);
  // 512 blocks x 4 waves x 32 rows = 65536 rows
  if (ws_interp) {
    linear_bnstats_rq<<<dim3(TQ / 128), dim3(256), 0, stream>>>(interp, W, bias, out, accum);
  } else {
    linear_bnstats_ma<<<dim3(TQ / 128), dim3(256), 0, stream>>>(interp, W, bias, out, accum);
  }
  bn_final<<<dim3((TQ * DD) / (4 * 256)), dim3(256), 0, stream>>>(out, accum, gamma, beta);
}